// Round 3
// baseline (1002.853 us; speedup 1.0000x reference)
//
#include <hip/hip_runtime.h>
#include <math.h>

#define B_ 64
#define T_ 512
#define E_ 64
#define H_ 128
#define NH_ 8
#define KD_ 32
#define BT_ (B_ * T_)
#define NEG_ -1e9f

__device__ __forceinline__ float sigmoidf_(float x) {
    return 1.f / (1.f + __expf(-x));
}
__device__ __forceinline__ float tanhf_(float x) {
    return 1.f - 2.f / (1.f + __expf(2.f * x));
}

// DPP quad-perm lane swaps (VALU, no LDS): xor1 = [1,0,3,2], xor2 = [2,3,0,1]
__device__ __forceinline__ float qswap1(float x) {
    return __int_as_float(__builtin_amdgcn_mov_dpp(__float_as_int(x), 0xB1, 0xF, 0xF, true));
}
__device__ __forceinline__ float qswap2(float x) {
    return __int_as_float(__builtin_amdgcn_mov_dpp(__float_as_int(x), 0x4E, 0xF, 0xF, true));
}

// Force-VGPR fmac: dst += a*b with all operands pinned to arch VGPRs.
// Non-volatile, register-only -> compiler can still schedule freely, but the
// register allocator cannot park a/b in AGPRs (round-2 failure: VGPR_Count=84
// proved u[] lived in AGPRs with per-use copy traffic).
#define FMAC_V(acc, a, b) \
    asm("v_fmac_f32 %0, %1, %2" : "+v"(acc) : "v"(a), "v"(b))

// ---------------------------------------------------------------------------
// Generic f32 GEMM: C[M][N] = A[M][K] @ B[K][N] + bias[N]
// GATHER: A row m = emb[gidx[m]] (K = E row stride)
// PERM (requires N==512): output column n' holds input column (n'&3)*128+(n'>>2)
//   i.e. gate-major -> unit-major layout for the LSTM xw staging.
// Tile 128x128, 256 threads, 8x8 micro, K-chunk 16.
// ---------------------------------------------------------------------------
template <bool GATHER, bool PERM>
__global__ __launch_bounds__(256, 3) void gemm_f32(
    const float* __restrict__ A, const int* __restrict__ gidx,
    const float* __restrict__ emb, const float* __restrict__ Bm,
    const float* __restrict__ bias, float* __restrict__ C,
    int M, int N, int K)
{
    __shared__ __align__(16) float As[16][132];
    __shared__ __align__(16) float Bs[16][128];
    const int tid = threadIdx.x;
    const int tx = tid & 15, ty = tid >> 4;
    const int ntn = N >> 7;
    const int bm = blockIdx.x / ntn, bn = blockIdx.x % ntn;
    const int m0 = bm << 7, n0 = bn << 7;

    float acc[8][8];
#pragma unroll
    for (int i = 0; i < 8; ++i)
#pragma unroll
        for (int j = 0; j < 8; ++j) acc[i][j] = 0.f;

    const int ac4 = (tid & 3) << 2;   // A col within chunk (0,4,8,12)
    const int ar  = tid >> 2;         // A row (0..63), 2 passes
    const int bc4 = (tid & 31) << 2;  // B col (0..124)
    const int br  = tid >> 5;         // B row (0..7), 2 passes

    for (int k0 = 0; k0 < K; k0 += 16) {
        __syncthreads();
#pragma unroll
        for (int p = 0; p < 2; ++p) {
            const int r = ar + p * 64;
            const int gm = m0 + r;
            const float* src = GATHER
                ? (emb + (size_t)gidx[gm] * K + (k0 + ac4))
                : (A + (size_t)gm * K + (k0 + ac4));
            float4 v = *(const float4*)src;
            As[ac4 + 0][r] = v.x; As[ac4 + 1][r] = v.y;
            As[ac4 + 2][r] = v.z; As[ac4 + 3][r] = v.w;
        }
#pragma unroll
        for (int p = 0; p < 2; ++p) {
            const int rr = br + p * 8;
            if (PERM) {
                const float* brow = Bm + (size_t)(k0 + rr) * N;
                const int base = (n0 >> 2) + (tid & 31);
                Bs[rr][bc4 + 0] = brow[base];
                Bs[rr][bc4 + 1] = brow[128 + base];
                Bs[rr][bc4 + 2] = brow[256 + base];
                Bs[rr][bc4 + 3] = brow[384 + base];
            } else {
                float4 v = *(const float4*)(Bm + (size_t)(k0 + rr) * N + (n0 + bc4));
                *(float4*)&Bs[rr][bc4] = v;
            }
        }
        __syncthreads();
#pragma unroll
        for (int k = 0; k < 16; ++k) {
            float a[8], b[8];
            *(float4*)&a[0] = *(const float4*)&As[k][ty << 3];
            *(float4*)&a[4] = *(const float4*)&As[k][(ty << 3) + 4];
            *(float4*)&b[0] = *(const float4*)&Bs[k][tx << 3];
            *(float4*)&b[4] = *(const float4*)&Bs[k][(tx << 3) + 4];
#pragma unroll
            for (int i = 0; i < 8; ++i)
#pragma unroll
                for (int j = 0; j < 8; ++j)
                    acc[i][j] = fmaf(a[i], b[j], acc[i][j]);
        }
    }

    float bv[8];
#pragma unroll
    for (int j = 0; j < 8; ++j) {
        const int n = n0 + (tx << 3) + j;
        bv[j] = PERM ? bias[((n & 3) << 7) + (n >> 2)] : bias[n];
    }
#pragma unroll
    for (int i = 0; i < 8; ++i) {
        float* dst = C + (size_t)(m0 + (ty << 3) + i) * N + n0 + (tx << 3);
        float4 o0 = { acc[i][0] + bv[0], acc[i][1] + bv[1],
                      acc[i][2] + bv[2], acc[i][3] + bv[3] };
        float4 o1 = { acc[i][4] + bv[4], acc[i][5] + bv[5],
                      acc[i][6] + bv[6], acc[i][7] + bv[7] };
        *(float4*)dst = o0;
        *(float4*)(dst + 4) = o1;
    }
}

// ---------------------------------------------------------------------------
// Bidirectional LSTM scan. One WG per (batch, dir): 128 WGs, 512 threads.
// Thread (jj = tid>>2, ks = tid&3) computes all 4 gates of hidden unit jj
// over k-chunk [32ks, 32ks+32). U block (4 gates x 32 k = 128 f32) held in
// arch VGPRs (enforced by FMAC_V inline asm). Partial sums reduced over the
// 4-lane group via DPP quad-perm. h double-buffered in LDS, 1 barrier/t.
// xw pre-staged unit-major: xw[t][jj*4 + gate] (PERM gemm).
// ---------------------------------------------------------------------------
__global__ __launch_bounds__(512, 2) void lstm_scan(
    const int* __restrict__ seq,
    const float* __restrict__ xwf, const float* __restrict__ xwb,
    const float* __restrict__ Uf, const float* __restrict__ Ub,
    float* __restrict__ hcat)
{
    const int w = blockIdx.x;
    const int dir = w & 1, b = w >> 1;
    const float* xw = dir ? xwb : xwf;
    const float* U  = dir ? Ub  : Uf;
    const int tid = threadIdx.x;
    const int jj = tid >> 2, ks = tid & 3;

    __shared__ __align__(16) float hbuf[2][4][36];
    __shared__ float mkl[T_];

    // u[g][kk] = U[(32*ks+kk)][g*128 + jj]
    float u[4][32];
#pragma unroll
    for (int g = 0; g < 4; ++g)
#pragma unroll
        for (int kk = 0; kk < 32; ++kk)
            u[g][kk] = U[(size_t)(32 * ks + kk) * 512 + g * 128 + jj];

    mkl[tid] = (seq[b * T_ + tid] != 0) ? 1.f : 0.f;
    if (tid < 2 * 4 * 36) ((float*)hbuf)[tid] = 0.f;

    float h_cur = 0.f, c_cur = 0.f;
    float* ho = hcat + (size_t)b * T_ * 256 + dir * 128;
    const float* xr = xw + (size_t)b * T_ * 512;

    __syncthreads();

    int te = dir ? (T_ - 1) : 0;
    float4 xwv = *(const float4*)&xr[(size_t)te * 512 + jj * 4];

    int p = 0;
    for (int t = 0; t < T_; ++t) {
        const int te_n  = dir ? (te - 1) : (te + 1);
        const int te_pf = (t == T_ - 1) ? te : te_n;
        const float4 xw_n = *(const float4*)&xr[(size_t)te_pf * 512 + jj * 4];

        float a0 = 0.f, a1 = 0.f, a2 = 0.f, a3 = 0.f;
        const float* hc = hbuf[p][ks];
#pragma unroll
        for (int c = 0; c < 8; ++c) {
            const float4 h4 = *(const float4*)&hc[c * 4];
            FMAC_V(a0, h4.x, u[0][c*4+0]); FMAC_V(a0, h4.y, u[0][c*4+1]);
            FMAC_V(a0, h4.z, u[0][c*4+2]); FMAC_V(a0, h4.w, u[0][c*4+3]);
            FMAC_V(a1, h4.x, u[1][c*4+0]); FMAC_V(a1, h4.y, u[1][c*4+1]);
            FMAC_V(a1, h4.z, u[1][c*4+2]); FMAC_V(a1, h4.w, u[1][c*4+3]);
            FMAC_V(a2, h4.x, u[2][c*4+0]); FMAC_V(a2, h4.y, u[2][c*4+1]);
            FMAC_V(a2, h4.z, u[2][c*4+2]); FMAC_V(a2, h4.w, u[2][c*4+3]);
            FMAC_V(a3, h4.x, u[3][c*4+0]); FMAC_V(a3, h4.y, u[3][c*4+1]);
            FMAC_V(a3, h4.z, u[3][c*4+2]); FMAC_V(a3, h4.w, u[3][c*4+3]);
        }
        // butterfly over the 4-lane group (DPP, stays on VALU)
        a0 += qswap1(a0); a0 += qswap2(a0);
        a1 += qswap1(a1); a1 += qswap2(a1);
        a2 += qswap1(a2); a2 += qswap2(a2);
        a3 += qswap1(a3); a3 += qswap2(a3);

        const float zi = xwv.x + a0, zf = xwv.y + a1;
        const float zg = xwv.z + a2, zo = xwv.w + a3;
        const float cn = fmaf(sigmoidf_(zf), c_cur, sigmoidf_(zi) * tanhf_(zg));
        const float hn = sigmoidf_(zo) * tanhf_(cn);
        const float m  = mkl[te];
        const float hm = (m > 0.5f) ? hn : h_cur;
        c_cur = (m > 0.5f) ? cn : c_cur;
        h_cur = hm;

        if ((jj >> 5) == ks) hbuf[1 - p][ks][jj & 31] = hm;
        if (ks == 0) ho[(size_t)te * 256 + jj] = hm;
        __syncthreads();
        p ^= 1; te = te_n; xwv = xw_n;
    }
}

// ---------------------------------------------------------------------------
// Fused flash-style attention. One WG per (b, head): 512 WGs, 256 threads.
// ---------------------------------------------------------------------------
__global__ __launch_bounds__(256, 2) void attn_fused(
    const int* __restrict__ seq,
    const float* __restrict__ q, const float* __restrict__ kk,
    const float* __restrict__ vv, float* __restrict__ ctx)
{
    const int wg = blockIdx.x;
    const int b = wg >> 3, h = wg & 7;
    const int tid = threadIdx.x;

    __shared__ __align__(16) float Ks[16][32];
    __shared__ __align__(16) float Vs[16][32];
    __shared__ float mk[16];

    float qA[32], qB[32];
    {
        const float* qp  = q + (((size_t)(b * T_) + tid) * NH_ + h) * KD_;
        const float* qp2 = qp + (size_t)256 * NH_ * KD_;
#pragma unroll
        for (int k = 0; k < 32; k += 4) {
            float4 v0 = *(const float4*)(qp + k);
            float4 v1 = *(const float4*)(qp2 + k);
            qA[k] = v0.x; qA[k + 1] = v0.y; qA[k + 2] = v0.z; qA[k + 3] = v0.w;
            qB[k] = v1.x; qB[k + 1] = v1.y; qB[k + 2] = v1.z; qB[k + 3] = v1.w;
        }
    }
    float ctxA[32], ctxB[32];
#pragma unroll
    for (int k = 0; k < 32; ++k) { ctxA[k] = 0.f; ctxB[k] = 0.f; }
    float mA = -1e30f, mB = -1e30f, lA = 0.f, lB = 0.f;

    const int lr = (tid & 127) >> 3;
    const int lc = (tid & 7) << 2;
    const bool loadV = (tid >= 128);

    for (int c = 0; c < T_ / 16; ++c) {
        const int s0 = c << 4;
        __syncthreads();
        {
            const float* src = (loadV ? vv : kk) +
                (((size_t)(b * T_) + s0 + lr) * NH_ + h) * KD_ + lc;
            float4 v = *(const float4*)src;
            if (loadV) *(float4*)&Vs[lr][lc] = v;
            else       *(float4*)&Ks[lr][lc] = v;
            if (tid < 16) mk[tid] = (seq[b * T_ + s0 + tid] != 0) ? 0.f : 1.f;
        }
        __syncthreads();

        float sA[16], sB[16];
#pragma unroll
        for (int s = 0; s < 16; ++s) {
            float dA = 0.f, dB = 0.f;
#pragma unroll
            for (int k = 0; k < 32; k += 4) {
                float4 k4 = *(const float4*)&Ks[s][k];
                dA = fmaf(k4.x, qA[k], dA); dA = fmaf(k4.y, qA[k + 1], dA);
                dA = fmaf(k4.z, qA[k + 2], dA); dA = fmaf(k4.w, qA[k + 3], dA);
                dB = fmaf(k4.x, qB[k], dB); dB = fmaf(k4.y, qB[k + 1], dB);
                dB = fmaf(k4.z, qB[k + 2], dB); dB = fmaf(k4.w, qB[k + 3], dB);
            }
            const float SCL = 0.17677669529663687f; // 1/sqrt(32)
            const bool masked = (mk[s] > 0.5f);
            sA[s] = masked ? NEG_ : dA * SCL;
            sB[s] = masked ? NEG_ : dB * SCL;
        }
        float cmA = sA[0], cmB = sB[0];
#pragma unroll
        for (int s = 1; s < 16; ++s) {
            cmA = fmaxf(cmA, sA[s]); cmB = fmaxf(cmB, sB[s]);
        }
        const float mnA = fmaxf(mA, cmA), mnB = fmaxf(mB, cmB);
        const float alA = __expf(mA - mnA), alB = __expf(mB - mnB);
        float psA = 0.f, psB = 0.f;
#pragma unroll
        for (int s = 0; s < 16; ++s) {
            float pa = __expf(sA[s] - mnA); sA[s] = pa; psA += pa;
            float pb = __expf(sB[s] - mnB); sB[s] = pb; psB += pb;
        }
        lA = fmaf(lA, alA, psA); lB = fmaf(lB, alB, psB);
        mA = mnA; mB = mnB;
#pragma unroll
        for (int k = 0; k < 32; ++k) { ctxA[k] *= alA; ctxB[k] *= alB; }
#pragma unroll
        for (int s = 0; s < 16; ++s) {
#pragma unroll
            for (int k = 0; k < 32; k += 4) {
                float4 v4 = *(const float4*)&Vs[s][k];
                ctxA[k]     = fmaf(sA[s], v4.x, ctxA[k]);
                ctxA[k + 1] = fmaf(sA[s], v4.y, ctxA[k + 1]);
                ctxA[k + 2] = fmaf(sA[s], v4.z, ctxA[k + 2]);
                ctxA[k + 3] = fmaf(sA[s], v4.w, ctxA[k + 3]);
                ctxB[k]     = fmaf(sB[s], v4.x, ctxB[k]);
                ctxB[k + 1] = fmaf(sB[s], v4.y, ctxB[k + 1]);
                ctxB[k + 2] = fmaf(sB[s], v4.z, ctxB[k + 2]);
                ctxB[k + 3] = fmaf(sB[s], v4.w, ctxB[k + 3]);
            }
        }
    }

    const float iA = 1.f / lA, iB = 1.f / lB;
    float* dA_ = ctx + (((size_t)(b * T_) + tid) * NH_ + h) * KD_;
    float* dB_ = dA_ + (size_t)256 * NH_ * KD_;
#pragma unroll
    for (int k = 0; k < 32; k += 4) {
        float4 o0 = { ctxA[k] * iA, ctxA[k + 1] * iA,
                      ctxA[k + 2] * iA, ctxA[k + 3] * iA };
        float4 o1 = { ctxB[k] * iB, ctxB[k + 1] * iB,
                      ctxB[k + 2] * iB, ctxB[k + 3] * iB };
        *(float4*)(dA_ + k) = o0;
        *(float4*)(dB_ + k) = o1;
    }
}

// ---------------------------------------------------------------------------
// Masked avg + max pooling over t. One WG per batch, 256 threads (one per d).
// ---------------------------------------------------------------------------
__global__ void pool_kernel(const int* __restrict__ seq,
                            const float* __restrict__ att,
                            float* __restrict__ p)
{
    const int b = blockIdx.x;
    const int d = threadIdx.x;
    __shared__ float mk[T_];
    for (int t = d; t < T_; t += 256)
        mk[t] = (seq[b * T_ + t] != 0) ? 1.f : 0.f;
    __syncthreads();
    float sum = 0.f, mx = NEG_, cnt = 0.f;
    for (int t = 0; t < T_; ++t) {
        const float a = att[((size_t)b * T_ + t) * 256 + d];
        const float m = mk[t];
        cnt += m;
        sum = fmaf(m, a, sum);
        mx = fmaxf(mx, (m > 0.5f) ? a : NEG_);
    }
    p[b * 512 + d] = sum / fmaxf(cnt, 1.f);
    p[b * 512 + 256 + d] = mx;
}

// ---------------------------------------------------------------------------
// MLP head: p(512) -> relu(256) -> relu(128) -> out(128). One WG per batch.
// ---------------------------------------------------------------------------
__global__ void mlp_kernel(const float* __restrict__ p,
                           const float* __restrict__ W1, const float* __restrict__ b1,
                           const float* __restrict__ W2, const float* __restrict__ b2,
                           const float* __restrict__ W3, const float* __restrict__ b3,
                           float* __restrict__ out)
{
    const int b = blockIdx.x;
    const int tid = threadIdx.x;
    __shared__ float pl[512];
    __shared__ float x1l[256];
    __shared__ float x2l[128];
    pl[tid] = p[b * 512 + tid];
    pl[tid + 256] = p[b * 512 + 256 + tid];
    __syncthreads();
    {
        float acc = b1[tid];
        for (int k = 0; k < 512; ++k) acc = fmaf(pl[k], W1[k * 256 + tid], acc);
        x1l[tid] = fmaxf(acc, 0.f);
    }
    __syncthreads();
    if (tid < 128) {
        float acc = b2[tid];
        for (int k = 0; k < 256; ++k) acc = fmaf(x1l[k], W2[k * 128 + tid], acc);
        x2l[tid] = fmaxf(acc, 0.f);
    }
    __syncthreads();
    if (tid < 128) {
        float acc = b3[tid];
        for (int k = 0; k < 128; ++k) acc = fmaf(x2l[k], W3[k * 128 + tid], acc);
        out[b * 128 + tid] = acc;
    }
}

// ---------------------------------------------------------------------------
extern "C" void kernel_launch(void* const* d_in, const int* in_sizes, int n_in,
                              void* d_out, int out_size, void* d_ws, size_t ws_size,
                              hipStream_t stream)
{
    (void)in_sizes; (void)n_in; (void)out_size; (void)ws_size;
    const int*   seq = (const int*)d_in[0];
    const float* emb = (const float*)d_in[1];
    const float* Wf  = (const float*)d_in[2];
    const float* Uf  = (const float*)d_in[3];
    const float* bf  = (const float*)d_in[4];
    const float* Wb  = (const float*)d_in[5];
    const float* Ub  = (const float*)d_in[6];
    const float* bb  = (const float*)d_in[7];
    const float* Wq  = (const float*)d_in[8];
    const float* bq  = (const float*)d_in[9];
    const float* Wk  = (const float*)d_in[10];
    const float* bk  = (const float*)d_in[11];
    const float* Wv  = (const float*)d_in[12];
    const float* bv  = (const float*)d_in[13];
    const float* Wo  = (const float*)d_in[14];
    const float* bo  = (const float*)d_in[15];
    const float* W1  = (const float*)d_in[16];
    const float* b1  = (const float*)d_in[17];
    const float* W2  = (const float*)d_in[18];
    const float* b2  = (const float*)d_in[19];
    const float* W3  = (const float*)d_in[20];
    const float* b3  = (const float*)d_in[21];
    float* out = (float*)d_out;
    float* ws  = (float*)d_ws;

    // workspace layout (floats)
    float* xw_f = ws;                   // 16,777,216  (BT*512)
    float* xw_b = ws + 16777216;        // 16,777,216
    float* hcat = ws + 33554432;        //  8,388,608  (BT*256)
    // reuse of xw region after the scan:
    float* qb   = ws;                   // 8,388,608
    float* kb   = ws + 8388608;
    float* vb   = ws + 16777216;
    float* cxb  = ws + 25165824;
    float* attb = ws + 33554432;        // reuses hcat (dead after QKV)
    float* pb   = ws + 41943040;        // 32,768

    const dim3 blk256(256), blk512(512);

    // x@W + b (embedding gathered), both directions, unit-major gate layout
    gemm_f32<true, true><<<dim3((BT_ / 128) * (512 / 128)), blk256, 0, stream>>>(
        nullptr, seq, emb, Wf, bf, xw_f, BT_, 512, 64);
    gemm_f32<true, true><<<dim3((BT_ / 128) * (512 / 128)), blk256, 0, stream>>>(
        nullptr, seq, emb, Wb, bb, xw_b, BT_, 512, 64);

    // bidirectional LSTM scan
    lstm_scan<<<dim3(128), blk512, 0, stream>>>(seq, xw_f, xw_b, Uf, Ub, hcat);

    // QKV projections
    gemm_f32<false, false><<<dim3((BT_ / 128) * (256 / 128)), blk256, 0, stream>>>(
        hcat, nullptr, nullptr, Wq, bq, qb, BT_, 256, 256);
    gemm_f32<false, false><<<dim3((BT_ / 128) * (256 / 128)), blk256, 0, stream>>>(
        hcat, nullptr, nullptr, Wk, bk, kb, BT_, 256, 256);
    gemm_f32<false, false><<<dim3((BT_ / 128) * (256 / 128)), blk256, 0, stream>>>(
        hcat, nullptr, nullptr, Wv, bv, vb, BT_, 256, 256);

    // fused attention
    attn_fused<<<dim3(B_ * NH_), blk256, 0, stream>>>(seq, qb, kb, vb, cxb);

    // attention output projection
    gemm_f32<false, false><<<dim3((BT_ / 128) * (256 / 128)), blk256, 0, stream>>>(
        cxb, nullptr, nullptr, Wo, bo, attb, BT_, 256, 256);

    // masked pooling + MLP head
    pool_kernel<<<dim3(B_), blk256, 0, stream>>>(seq, attb, pb);
    mlp_kernel<<<dim3(B_), blk256, 0, stream>>>(pb, W1, b1, W2, b2, W3, b3, out);
}

// Round 4
// 911.416 us; speedup vs baseline: 1.1003x; 1.1003x over previous
//
#include <hip/hip_runtime.h>
#include <math.h>

#define B_ 64
#define T_ 512
#define E_ 64
#define H_ 128
#define NH_ 8
#define KD_ 32
#define BT_ (B_ * T_)
#define NEG_ -1e9f

typedef __attribute__((ext_vector_type(8))) short bf16x8_t;
typedef __attribute__((ext_vector_type(4))) float f32x4_t;
typedef unsigned short ushort_t;
typedef unsigned int uint_t;

__device__ __forceinline__ float sigmoidf_(float x) {
    return 1.f / (1.f + __expf(-x));
}
__device__ __forceinline__ float tanhf_(float x) {
    return 1.f - 2.f / (1.f + __expf(2.f * x));
}

__device__ __forceinline__ ushort_t bf16_rne(float x) {
    uint_t u = __float_as_uint(x);
    uint_t r = (u + 0x7FFFu + ((u >> 16) & 1u)) >> 16;
    return (ushort_t)r;
}
__device__ __forceinline__ float bf16_to_f(ushort_t h) {
    return __uint_as_float(((uint_t)h) << 16);
}
__device__ __forceinline__ void split_bf16(float x, ushort_t& h, ushort_t& l) {
    h = bf16_rne(x);
    l = bf16_rne(x - bf16_to_f(h));
}

// DPP quad-perm lane swaps (VALU, no LDS): xor1 = [1,0,3,2], xor2 = [2,3,0,1]
__device__ __forceinline__ float qswap1(float x) {
    return __int_as_float(__builtin_amdgcn_mov_dpp(__float_as_int(x), 0xB1, 0xF, 0xF, true));
}
__device__ __forceinline__ float qswap2(float x) {
    return __int_as_float(__builtin_amdgcn_mov_dpp(__float_as_int(x), 0x4E, 0xF, 0xF, true));
}

// ---------------------------------------------------------------------------
// Generic f32 GEMM (kept for the two x@W stagings, K=64).
// GATHER: A row m = emb[gidx[m]].  PERM (N==512): out col n' holds input
// column (n'&3)*128 + (n'>>2)  (gate-major -> unit-major for LSTM).
// ---------------------------------------------------------------------------
template <bool GATHER, bool PERM>
__global__ __launch_bounds__(256, 3) void gemm_f32(
    const float* __restrict__ A, const int* __restrict__ gidx,
    const float* __restrict__ emb, const float* __restrict__ Bm,
    const float* __restrict__ bias, float* __restrict__ C,
    int M, int N, int K)
{
    __shared__ __align__(16) float As[16][132];
    __shared__ __align__(16) float Bs[16][128];
    const int tid = threadIdx.x;
    const int tx = tid & 15, ty = tid >> 4;
    const int ntn = N >> 7;
    const int bm = blockIdx.x / ntn, bn = blockIdx.x % ntn;
    const int m0 = bm << 7, n0 = bn << 7;

    float acc[8][8];
#pragma unroll
    for (int i = 0; i < 8; ++i)
#pragma unroll
        for (int j = 0; j < 8; ++j) acc[i][j] = 0.f;

    const int ac4 = (tid & 3) << 2;
    const int ar  = tid >> 2;
    const int bc4 = (tid & 31) << 2;
    const int br  = tid >> 5;

    for (int k0 = 0; k0 < K; k0 += 16) {
        __syncthreads();
#pragma unroll
        for (int p = 0; p < 2; ++p) {
            const int r = ar + p * 64;
            const int gm = m0 + r;
            const float* src = GATHER
                ? (emb + (size_t)gidx[gm] * K + (k0 + ac4))
                : (A + (size_t)gm * K + (k0 + ac4));
            float4 v = *(const float4*)src;
            As[ac4 + 0][r] = v.x; As[ac4 + 1][r] = v.y;
            As[ac4 + 2][r] = v.z; As[ac4 + 3][r] = v.w;
        }
#pragma unroll
        for (int p = 0; p < 2; ++p) {
            const int rr = br + p * 8;
            if (PERM) {
                const float* brow = Bm + (size_t)(k0 + rr) * N;
                const int base = (n0 >> 2) + (tid & 31);
                Bs[rr][bc4 + 0] = brow[base];
                Bs[rr][bc4 + 1] = brow[128 + base];
                Bs[rr][bc4 + 2] = brow[256 + base];
                Bs[rr][bc4 + 3] = brow[384 + base];
            } else {
                float4 v = *(const float4*)(Bm + (size_t)(k0 + rr) * N + (n0 + bc4));
                *(float4*)&Bs[rr][bc4] = v;
            }
        }
        __syncthreads();
#pragma unroll
        for (int k = 0; k < 16; ++k) {
            float a[8], b[8];
            *(float4*)&a[0] = *(const float4*)&As[k][ty << 3];
            *(float4*)&a[4] = *(const float4*)&As[k][(ty << 3) + 4];
            *(float4*)&b[0] = *(const float4*)&Bs[k][tx << 3];
            *(float4*)&b[4] = *(const float4*)&Bs[k][(tx << 3) + 4];
#pragma unroll
            for (int i = 0; i < 8; ++i)
#pragma unroll
                for (int j = 0; j < 8; ++j)
                    acc[i][j] = fmaf(a[i], b[j], acc[i][j]);
        }
    }

    float bv[8];
#pragma unroll
    for (int j = 0; j < 8; ++j) {
        const int n = n0 + (tx << 3) + j;
        bv[j] = PERM ? bias[((n & 3) << 7) + (n >> 2)] : bias[n];
    }
#pragma unroll
    for (int i = 0; i < 8; ++i) {
        float* dst = C + (size_t)(m0 + (ty << 3) + i) * N + n0 + (tx << 3);
        float4 o0 = { acc[i][0] + bv[0], acc[i][1] + bv[1],
                      acc[i][2] + bv[2], acc[i][3] + bv[3] };
        float4 o1 = { acc[i][4] + bv[4], acc[i][5] + bv[5],
                      acc[i][6] + bv[6], acc[i][7] + bv[7] };
        *(float4*)dst = o0;
        *(float4*)(dst + 4) = o1;
    }
}

// ---------------------------------------------------------------------------
// Weight transpose + bf16 hi/lo split: W[256][256] (k-major) -> Bh/Bl[n][k].
// ---------------------------------------------------------------------------
__global__ void wconv(const float* __restrict__ W,
                      ushort_t* __restrict__ Bh, ushort_t* __restrict__ Bl)
{
    const int k = blockIdx.x, n = threadIdx.x;
    float v = W[k * 256 + n];
    ushort_t h, l;
    split_bf16(v, h, l);
    Bh[n * 256 + k] = h;
    Bl[n * 256 + k] = l;
}

// ---------------------------------------------------------------------------
// bf16x3 MFMA GEMM: C[M][N] = A@B + bias, K=256 fixed.
// A given as hi/lo bf16 [M][256]; B as hi/lo bf16 TRANSPOSED [N][256].
// Tile 128x128, 256 threads = 4 waves, wave tile 64x64 (4x4 16x16 frags).
// a*b ~= ah*bh + ah*bl + al*bh  (f32 accumulate, fp32-class precision).
// LDS rows padded to 40 ushorts -> conflict-free ds_read_b128.
// ---------------------------------------------------------------------------
__global__ __launch_bounds__(256, 2) void gemm_mfma3(
    const ushort_t* __restrict__ Ah, const ushort_t* __restrict__ Al,
    const ushort_t* __restrict__ Bh, const ushort_t* __restrict__ Bl,
    const float* __restrict__ bias, float* __restrict__ C,
    int M, int N)
{
    __shared__ __align__(16) ushort_t Alds[2][128 * 40];
    __shared__ __align__(16) ushort_t Blds[2][128 * 40];

    const int tid = threadIdx.x;
    const int ntn = N >> 7;
    const int bm = blockIdx.x / ntn, bn = blockIdx.x % ntn;
    const int m0 = bm << 7, n0 = bn << 7;

    const int w = tid >> 6;          // wave 0..3
    const int wr = w >> 1, wc = w & 1;
    const int lane = tid & 63;
    const int fr = lane & 15, kg = lane >> 4;

    const int sr = tid >> 1;         // staging row 0..127
    const int sh = (tid & 1) << 4;   // staging k offset (ushorts): 0 / 16

    f32x4_t acc[4][4];
#pragma unroll
    for (int i = 0; i < 4; ++i)
#pragma unroll
        for (int j = 0; j < 4; ++j) acc[i][j] = (f32x4_t){0.f, 0.f, 0.f, 0.f};

    for (int ks = 0; ks < 8; ++ks) {
        const int k0 = ks << 5;
        __syncthreads();
        {
            const size_t ga = (size_t)(m0 + sr) * 256 + k0 + sh;
            const size_t gb = (size_t)(n0 + sr) * 256 + k0 + sh;
            const int ld = sr * 40 + sh;
            const uint4* pah = (const uint4*)(Ah + ga);
            const uint4* pal = (const uint4*)(Al + ga);
            const uint4* pbh = (const uint4*)(Bh + gb);
            const uint4* pbl = (const uint4*)(Bl + gb);
            uint4* qah = (uint4*)&Alds[0][ld];
            uint4* qal = (uint4*)&Alds[1][ld];
            uint4* qbh = (uint4*)&Blds[0][ld];
            uint4* qbl = (uint4*)&Blds[1][ld];
            qah[0] = pah[0]; qah[1] = pah[1];
            qal[0] = pal[0]; qal[1] = pal[1];
            qbh[0] = pbh[0]; qbh[1] = pbh[1];
            qbl[0] = pbl[0]; qbl[1] = pbl[1];
        }
        __syncthreads();

        bf16x8_t ah[4], al[4], bh[4], bl[4];
#pragma unroll
        for (int i = 0; i < 4; ++i) {
            const int ra = (wr * 64 + i * 16 + fr) * 40 + kg * 8;
            const int rb = (wc * 64 + i * 16 + fr) * 40 + kg * 8;
            ah[i] = *(const bf16x8_t*)&Alds[0][ra];
            al[i] = *(const bf16x8_t*)&Alds[1][ra];
            bh[i] = *(const bf16x8_t*)&Blds[0][rb];
            bl[i] = *(const bf16x8_t*)&Blds[1][rb];
        }
#pragma unroll
        for (int i = 0; i < 4; ++i)
#pragma unroll
            for (int j = 0; j < 4; ++j) {
                acc[i][j] = __builtin_amdgcn_mfma_f32_16x16x32_bf16(
                    ah[i], bh[j], acc[i][j], 0, 0, 0);
                acc[i][j] = __builtin_amdgcn_mfma_f32_16x16x32_bf16(
                    ah[i], bl[j], acc[i][j], 0, 0, 0);
                acc[i][j] = __builtin_amdgcn_mfma_f32_16x16x32_bf16(
                    al[i], bh[j], acc[i][j], 0, 0, 0);
            }
    }

#pragma unroll
    for (int j = 0; j < 4; ++j) {
        const int col = n0 + wc * 64 + j * 16 + fr;
        const float bv = bias[col];
#pragma unroll
        for (int i = 0; i < 4; ++i) {
#pragma unroll
            for (int r = 0; r < 4; ++r) {
                const int row = m0 + wr * 64 + i * 16 + kg * 4 + r;
                C[(size_t)row * N + col] = acc[i][j][r] + bv;
            }
        }
    }
}

// ---------------------------------------------------------------------------
// Bidirectional LSTM scan. One WG per (batch, dir): 128 WGs, 512 threads.
// launch_bounds(512,1): only 1 WG/CU is resident anyway (128 WGs < 256 CUs);
// raises per-wave reg budget to 512 so u[128] stays in ARCH VGPRs (rounds
// 1-3 failure: at (512,2) budget=256 the allocator parked u in AGPRs).
// Emits h directly as bf16 hi/lo pairs for the downstream MFMA GEMMs.
// ---------------------------------------------------------------------------
__global__ __launch_bounds__(512, 1) void lstm_scan(
    const int* __restrict__ seq,
    const float* __restrict__ xwf, const float* __restrict__ xwb,
    const float* __restrict__ Uf, const float* __restrict__ Ub,
    ushort_t* __restrict__ hch, ushort_t* __restrict__ hcl)
{
    const int w = blockIdx.x;
    const int dir = w & 1, b = w >> 1;
    const float* xw = dir ? xwb : xwf;
    const float* U  = dir ? Ub  : Uf;
    const int tid = threadIdx.x;
    const int jj = tid >> 2, ks = tid & 3;

    __shared__ __align__(16) float hbuf[2][4][36];
    __shared__ float mkl[T_];

    // u[g][kk] = U[(32*ks+kk)][g*128 + jj]
    float u[4][32];
#pragma unroll
    for (int g = 0; g < 4; ++g)
#pragma unroll
        for (int kk = 0; kk < 32; ++kk)
            u[g][kk] = U[(size_t)(32 * ks + kk) * 512 + g * 128 + jj];

    mkl[tid] = (seq[b * T_ + tid] != 0) ? 1.f : 0.f;
    if (tid < 2 * 4 * 36) ((float*)hbuf)[tid] = 0.f;

    float h_cur = 0.f, c_cur = 0.f;
    ushort_t* hoh = hch + (size_t)b * T_ * 256 + dir * 128;
    ushort_t* hol = hcl + (size_t)b * T_ * 256 + dir * 128;
    const float* xr = xw + (size_t)b * T_ * 512;

    __syncthreads();

    int te = dir ? (T_ - 1) : 0;
    float4 xwv = *(const float4*)&xr[(size_t)te * 512 + jj * 4];

    int p = 0;
    for (int t = 0; t < T_; ++t) {
        const int te_n  = dir ? (te - 1) : (te + 1);
        const int te_pf = (t == T_ - 1) ? te : te_n;
        const float4 xw_n = *(const float4*)&xr[(size_t)te_pf * 512 + jj * 4];

        float a0 = 0.f, a1 = 0.f, a2 = 0.f, a3 = 0.f;
        const float* hc = hbuf[p][ks];
#pragma unroll
        for (int c = 0; c < 8; ++c) {
            const float4 h4 = *(const float4*)&hc[c * 4];
            a0 = fmaf(h4.x, u[0][c*4+0], a0); a0 = fmaf(h4.y, u[0][c*4+1], a0);
            a0 = fmaf(h4.z, u[0][c*4+2], a0); a0 = fmaf(h4.w, u[0][c*4+3], a0);
            a1 = fmaf(h4.x, u[1][c*4+0], a1); a1 = fmaf(h4.y, u[1][c*4+1], a1);
            a1 = fmaf(h4.z, u[1][c*4+2], a1); a1 = fmaf(h4.w, u[1][c*4+3], a1);
            a2 = fmaf(h4.x, u[2][c*4+0], a2); a2 = fmaf(h4.y, u[2][c*4+1], a2);
            a2 = fmaf(h4.z, u[2][c*4+2], a2); a2 = fmaf(h4.w, u[2][c*4+3], a2);
            a3 = fmaf(h4.x, u[3][c*4+0], a3); a3 = fmaf(h4.y, u[3][c*4+1], a3);
            a3 = fmaf(h4.z, u[3][c*4+2], a3); a3 = fmaf(h4.w, u[3][c*4+3], a3);
        }
        a0 += qswap1(a0); a0 += qswap2(a0);
        a1 += qswap1(a1); a1 += qswap2(a1);
        a2 += qswap1(a2); a2 += qswap2(a2);
        a3 += qswap1(a3); a3 += qswap2(a3);

        const float zi = xwv.x + a0, zf = xwv.y + a1;
        const float zg = xwv.z + a2, zo = xwv.w + a3;
        const float cn = fmaf(sigmoidf_(zf), c_cur, sigmoidf_(zi) * tanhf_(zg));
        const float hn = sigmoidf_(zo) * tanhf_(cn);
        const float m  = mkl[te];
        const float hm = (m > 0.5f) ? hn : h_cur;
        c_cur = (m > 0.5f) ? cn : c_cur;
        h_cur = hm;

        if ((jj >> 5) == ks) hbuf[1 - p][ks][jj & 31] = hm;
        if (ks == 0) {
            ushort_t hh, hl;
            split_bf16(hm, hh, hl);
            hoh[(size_t)te * 256 + jj] = hh;
            hol[(size_t)te * 256 + jj] = hl;
        }
        __syncthreads();
        p ^= 1; te = te_n; xwv = xw_n;
    }
}

// ---------------------------------------------------------------------------
// Fused flash-style attention. One WG per (b, head): 512 WGs, 256 threads.
// Emits ctx as bf16 hi/lo for the Wo MFMA GEMM.
// ---------------------------------------------------------------------------
__global__ __launch_bounds__(256, 2) void attn_fused(
    const int* __restrict__ seq,
    const float* __restrict__ q, const float* __restrict__ kk,
    const float* __restrict__ vv,
    ushort_t* __restrict__ cxh, ushort_t* __restrict__ cxl)
{
    const int wg = blockIdx.x;
    const int b = wg >> 3, h = wg & 7;
    const int tid = threadIdx.x;

    __shared__ __align__(16) float Ks[16][32];
    __shared__ __align__(16) float Vs[16][32];
    __shared__ float mk[16];

    float qA[32], qB[32];
    {
        const float* qp  = q + (((size_t)(b * T_) + tid) * NH_ + h) * KD_;
        const float* qp2 = qp + (size_t)256 * NH_ * KD_;
#pragma unroll
        for (int k = 0; k < 32; k += 4) {
            float4 v0 = *(const float4*)(qp + k);
            float4 v1 = *(const float4*)(qp2 + k);
            qA[k] = v0.x; qA[k + 1] = v0.y; qA[k + 2] = v0.z; qA[k + 3] = v0.w;
            qB[k] = v1.x; qB[k + 1] = v1.y; qB[k + 2] = v1.z; qB[k + 3] = v1.w;
        }
    }
    float ctxA[32], ctxB[32];
#pragma unroll
    for (int k = 0; k < 32; ++k) { ctxA[k] = 0.f; ctxB[k] = 0.f; }
    float mA = -1e30f, mB = -1e30f, lA = 0.f, lB = 0.f;

    const int lr = (tid & 127) >> 3;
    const int lc = (tid & 7) << 2;
    const bool loadV = (tid >= 128);

    for (int c = 0; c < T_ / 16; ++c) {
        const int s0 = c << 4;
        __syncthreads();
        {
            const float* src = (loadV ? vv : kk) +
                (((size_t)(b * T_) + s0 + lr) * NH_ + h) * KD_ + lc;
            float4 v = *(const float4*)src;
            if (loadV) *(float4*)&Vs[lr][lc] = v;
            else       *(float4*)&Ks[lr][lc] = v;
            if (tid < 16) mk[tid] = (seq[b * T_ + s0 + tid] != 0) ? 0.f : 1.f;
        }
        __syncthreads();

        float sA[16], sB[16];
#pragma unroll
        for (int s = 0; s < 16; ++s) {
            float dA = 0.f, dB = 0.f;
#pragma unroll
            for (int k = 0; k < 32; k += 4) {
                float4 k4 = *(const float4*)&Ks[s][k];
                dA = fmaf(k4.x, qA[k], dA); dA = fmaf(k4.y, qA[k + 1], dA);
                dA = fmaf(k4.z, qA[k + 2], dA); dA = fmaf(k4.w, qA[k + 3], dA);
                dB = fmaf(k4.x, qB[k], dB); dB = fmaf(k4.y, qB[k + 1], dB);
                dB = fmaf(k4.z, qB[k + 2], dB); dB = fmaf(k4.w, qB[k + 3], dB);
            }
            const float SCL = 0.17677669529663687f; // 1/sqrt(32)
            const bool masked = (mk[s] > 0.5f);
            sA[s] = masked ? NEG_ : dA * SCL;
            sB[s] = masked ? NEG_ : dB * SCL;
        }
        float cmA = sA[0], cmB = sB[0];
#pragma unroll
        for (int s = 1; s < 16; ++s) {
            cmA = fmaxf(cmA, sA[s]); cmB = fmaxf(cmB, sB[s]);
        }
        const float mnA = fmaxf(mA, cmA), mnB = fmaxf(mB, cmB);
        const float alA = __expf(mA - mnA), alB = __expf(mB - mnB);
        float psA = 0.f, psB = 0.f;
#pragma unroll
        for (int s = 0; s < 16; ++s) {
            float pa = __expf(sA[s] - mnA); sA[s] = pa; psA += pa;
            float pb = __expf(sB[s] - mnB); sB[s] = pb; psB += pb;
        }
        lA = fmaf(lA, alA, psA); lB = fmaf(lB, alB, psB);
        mA = mnA; mB = mnB;
#pragma unroll
        for (int k = 0; k < 32; ++k) { ctxA[k] *= alA; ctxB[k] *= alB; }
#pragma unroll
        for (int s = 0; s < 16; ++s) {
#pragma unroll
            for (int k = 0; k < 32; k += 4) {
                float4 v4 = *(const float4*)&Vs[s][k];
                ctxA[k]     = fmaf(sA[s], v4.x, ctxA[k]);
                ctxA[k + 1] = fmaf(sA[s], v4.y, ctxA[k + 1]);
                ctxA[k + 2] = fmaf(sA[s], v4.z, ctxA[k + 2]);
                ctxA[k + 3] = fmaf(sA[s], v4.w, ctxA[k + 3]);
                ctxB[k]     = fmaf(sB[s], v4.x, ctxB[k]);
                ctxB[k + 1] = fmaf(sB[s], v4.y, ctxB[k + 1]);
                ctxB[k + 2] = fmaf(sB[s], v4.z, ctxB[k + 2]);
                ctxB[k + 3] = fmaf(sB[s], v4.w, ctxB[k + 3]);
            }
        }
    }

    const float iA = 1.f / lA, iB = 1.f / lB;
    ushort_t* chA = cxh + (((size_t)(b * T_) + tid) * NH_ + h) * KD_;
    ushort_t* clA = cxl + (((size_t)(b * T_) + tid) * NH_ + h) * KD_;
    ushort_t* chB = chA + (size_t)256 * NH_ * KD_;
    ushort_t* clB = clA + (size_t)256 * NH_ * KD_;
#pragma unroll
    for (int k = 0; k < 32; ++k) {
        ushort_t hA, lA_, hB, lB_;
        split_bf16(ctxA[k] * iA, hA, lA_);
        split_bf16(ctxB[k] * iB, hB, lB_);
        chA[k] = hA; clA[k] = lA_;
        chB[k] = hB; clB[k] = lB_;
    }
}

// ---------------------------------------------------------------------------
// Masked avg + max pooling over t. One WG per batch, 256 threads (one per d).
// ---------------------------------------------------------------------------
__global__ void pool_kernel(const int* __restrict__ seq,
                            const float* __restrict__ att,
                            float* __restrict__ p)
{
    const int b = blockIdx.x;
    const int d = threadIdx.x;
    __shared__ float mk[T_];
    for (int t = d; t < T_; t += 256)
        mk[t] = (seq[b * T_ + t] != 0) ? 1.f : 0.f;
    __syncthreads();
    float sum = 0.f, mx = NEG_, cnt = 0.f;
    for (int t = 0; t < T_; ++t) {
        const float a = att[((size_t)b * T_ + t) * 256 + d];
        const float m = mk[t];
        cnt += m;
        sum = fmaf(m, a, sum);
        mx = fmaxf(mx, (m > 0.5f) ? a : NEG_);
    }
    p[b * 512 + d] = sum / fmaxf(cnt, 1.f);
    p[b * 512 + 256 + d] = mx;
}

// ---------------------------------------------------------------------------
// MLP head: p(512) -> relu(256) -> relu(128) -> out(128). One WG per batch.
// ---------------------------------------------------------------------------
__global__ void mlp_kernel(const float* __restrict__ p,
                           const float* __restrict__ W1, const float* __restrict__ b1,
                           const float* __restrict__ W2, const float* __restrict__ b2,
                           const float* __restrict__ W3, const float* __restrict__ b3,
                           float* __restrict__ out)
{
    const int b = blockIdx.x;
    const int tid = threadIdx.x;
    __shared__ float pl[512];
    __shared__ float x1l[256];
    __shared__ float x2l[128];
    pl[tid] = p[b * 512 + tid];
    pl[tid + 256] = p[b * 512 + 256 + tid];
    __syncthreads();
    {
        float acc = b1[tid];
        for (int k = 0; k < 512; ++k) acc = fmaf(pl[k], W1[k * 256 + tid], acc);
        x1l[tid] = fmaxf(acc, 0.f);
    }
    __syncthreads();
    if (tid < 128) {
        float acc = b2[tid];
        for (int k = 0; k < 256; ++k) acc = fmaf(x1l[k], W2[k * 128 + tid], acc);
        x2l[tid] = fmaxf(acc, 0.f);
    }
    __syncthreads();
    if (tid < 128) {
        float acc = b3[tid];
        for (int k = 0; k < 128; ++k) acc = fmaf(x2l[k], W3[k * 128 + tid], acc);
        out[b * 128 + tid] = acc;
    }
}

// ---------------------------------------------------------------------------
extern "C" void kernel_launch(void* const* d_in, const int* in_sizes, int n_in,
                              void* d_out, int out_size, void* d_ws, size_t ws_size,
                              hipStream_t stream)
{
    (void)in_sizes; (void)n_in; (void)out_size; (void)ws_size;
    const int*   seq = (const int*)d_in[0];
    const float* emb = (const float*)d_in[1];
    const float* Wf  = (const float*)d_in[2];
    const float* Uf  = (const float*)d_in[3];
    const float* bf  = (const float*)d_in[4];
    const float* Wb  = (const float*)d_in[5];
    const float* Ub  = (const float*)d_in[6];
    const float* bb  = (const float*)d_in[7];
    const float* Wq  = (const float*)d_in[8];
    const float* bq  = (const float*)d_in[9];
    const float* Wk  = (const float*)d_in[10];
    const float* bk  = (const float*)d_in[11];
    const float* Wv  = (const float*)d_in[12];
    const float* bv  = (const float*)d_in[13];
    const float* Wo  = (const float*)d_in[14];
    const float* bo  = (const float*)d_in[15];
    const float* W1  = (const float*)d_in[16];
    const float* b1  = (const float*)d_in[17];
    const float* W2  = (const float*)d_in[18];
    const float* b2  = (const float*)d_in[19];
    const float* W3  = (const float*)d_in[20];
    const float* b3  = (const float*)d_in[21];
    float* out = (float*)d_out;
    float* ws  = (float*)d_ws;

    // workspace layout (float offsets)
    float* xw_f = ws;                    // [0, 16777216)            BT*512 f32
    float* xw_b = ws + 16777216;         // [16777216, 33554432)     BT*512 f32
    // after scan, xw regions recycled:
    float* qb   = ws;                    // BT*256 f32
    float* kb   = ws + 8388608;
    float* vb   = ws + 16777216;
    // cx hi/lo pair lives in the old cxb region:
    ushort_t* cxh = (ushort_t*)(ws + 25165824);   // BT*256 bf16-hi
    ushort_t* cxl = cxh + (size_t)BT_ * 256;      // BT*256 bf16-lo
    // h hi/lo pair in the old hcat region; attb overwrites it later:
    ushort_t* hch = (ushort_t*)(ws + 33554432);
    ushort_t* hcl = hch + (size_t)BT_ * 256;
    float* attb = ws + 33554432;         // BT*256 f32 (over hch/hcl, dead then)
    float* pb   = ws + 41943040;         // B*512 f32
    // transposed/split weights: 8 x 65536 ushorts = 1 MB
    ushort_t* wt = (ushort_t*)(ws + 41975808);
    ushort_t* Wqh = wt + 0 * 65536, *Wql = wt + 1 * 65536;
    ushort_t* Wkh = wt + 2 * 65536, *Wkl = wt + 3 * 65536;
    ushort_t* Wvh = wt + 4 * 65536, *Wvl = wt + 5 * 65536;
    ushort_t* Woh = wt + 6 * 65536, *Wol = wt + 7 * 65536;

    const dim3 blk256(256), blk512(512);

    // weight transpose + bf16 hi/lo split (tiny)
    wconv<<<dim3(256), blk256, 0, stream>>>(Wq, Wqh, Wql);
    wconv<<<dim3(256), blk256, 0, stream>>>(Wk, Wkh, Wkl);
    wconv<<<dim3(256), blk256, 0, stream>>>(Wv, Wvh, Wvl);
    wconv<<<dim3(256), blk256, 0, stream>>>(Wo, Woh, Wol);

    // x@W + b (embedding gathered), both directions, unit-major gate layout
    gemm_f32<true, true><<<dim3((BT_ / 128) * (512 / 128)), blk256, 0, stream>>>(
        nullptr, seq, emb, Wf, bf, xw_f, BT_, 512, 64);
    gemm_f32<true, true><<<dim3((BT_ / 128) * (512 / 128)), blk256, 0, stream>>>(
        nullptr, seq, emb, Wb, bb, xw_b, BT_, 512, 64);

    // bidirectional LSTM scan -> h as bf16 hi/lo
    lstm_scan<<<dim3(128), blk512, 0, stream>>>(seq, xw_f, xw_b, Uf, Ub, hch, hcl);

    // QKV projections (bf16x3 MFMA)
    gemm_mfma3<<<dim3((BT_ / 128) * 2), blk256, 0, stream>>>(
        hch, hcl, Wqh, Wql, bq, qb, BT_, 256);
    gemm_mfma3<<<dim3((BT_ / 128) * 2), blk256, 0, stream>>>(
        hch, hcl, Wkh, Wkl, bk, kb, BT_, 256);
    gemm_mfma3<<<dim3((BT_ / 128) * 2), blk256, 0, stream>>>(
        hch, hcl, Wvh, Wvl, bv, vb, BT_, 256);

    // fused attention -> ctx as bf16 hi/lo
    attn_fused<<<dim3(B_ * NH_), blk256, 0, stream>>>(seq, qb, kb, vb, cxh, cxl);

    // attention output projection (bf16x3 MFMA)
    gemm_mfma3<<<dim3((BT_ / 128) * 2), blk256, 0, stream>>>(
        cxh, cxl, Woh, Wol, bo, attb, BT_, 256);

    // masked pooling + MLP head
    pool_kernel<<<dim3(B_), blk256, 0, stream>>>(seq, attb, pb);
    mlp_kernel<<<dim3(B_), blk256, 0, stream>>>(pb, W1, b1, W2, b2, W3, b3, out);
}